// Round 13
// baseline (348.372 us; speedup 1.0000x reference)
//
#include <hip/hip_runtime.h>
#include <hip/hip_bf16.h>

#define BB   256
#define NN   2207
#define MM   16
#define EE   16777216
#define CC1  12
#define CC2  4
#define HH1  256
#define HH2  64
#define KK1  (CC2*NN)          /* 8828 */
#define LN_EPS 1e-5f
#define BN_SCALE 0.9999950000374997f   /* 1/sqrt(1+1e-5) */
#define NBK  256               /* samples */
#define MAGIC 1946067ull       /* ceil(2^32/2207), exact for d < 564992 */
#define EPB  4096              /* edges per bin block */
#define TPB  512
#define EPT  (EPB/TPB)         /* 8 edges per thread */
#define NBLK (EE/EPB)          /* 4096 bin blocks */
#define GRP  4                 /* samples per bucket group */
#define NBG  (NBK/GRP)         /* 64 bucket groups */
#define RSPL 16                /* replay splits; 1024 replay blocks */
#define GNN  (GRP*NN)          /* 8828 acc entries */

static __device__ __forceinline__ unsigned bucket_of(int d) {
    return (unsigned)(((unsigned long long)(unsigned)d * MAGIC) >> 32);
}

// ===== PASS 1: fused gather + rank + scan + direct scatter (premultiplied recs) =====
// record = ( dst_key14 , v = x[src]*w )  -- replay is gather-free
__global__ __launch_bounds__(TPB, 8)
void k_place5(const int* __restrict__ src, const int* __restrict__ dst,
              const float* __restrict__ ew, const float* __restrict__ x,
              uint2* __restrict__ recs, unsigned short* __restrict__ stab)
{
    __shared__ unsigned int hist[NBG], start[NBG];
    const int t = threadIdx.x;
    if (t < NBG) hist[t] = 0;
    __syncthreads();

    const int i4base = blockIdx.x * (EPB/4);
    unsigned short key[EPT];     // dst key within 4-sample group (<8828)
    float          vv[EPT];      // x[src]*w
    unsigned short rk[EPT];      // intra-bucket rank (<4096)
    unsigned char  bk[EPT];      // bucket group (<64)
    #pragma unroll
    for (int q = 0; q < EPT/4; ++q) {
        int i4 = i4base + q*TPB + t;
        int4   s4 = reinterpret_cast<const int4*>(src)[i4];
        int4   d4 = reinterpret_cast<const int4*>(dst)[i4];
        float4 w4 = reinterpret_cast<const float4*>(ew)[i4];
        // issue all 4 gathers early (overlap with atomics below)
        float x0 = x[s4.x], x1 = x[s4.y], x2 = x[s4.z], x3 = x[s4.w];
        unsigned sm0 = bucket_of(d4.x), sm1 = bucket_of(d4.y);
        unsigned sm2 = bucket_of(d4.z), sm3 = bucket_of(d4.w);
        unsigned g0 = sm0 >> 2, g1 = sm1 >> 2, g2 = sm2 >> 2, g3 = sm3 >> 2;
        unsigned r0 = atomicAdd(&hist[g0], 1u);
        unsigned r1 = atomicAdd(&hist[g1], 1u);
        unsigned r2 = atomicAdd(&hist[g2], 1u);
        unsigned r3 = atomicAdd(&hist[g3], 1u);
        key[q*4+0] = (unsigned short)((unsigned)d4.x - (sm0 & ~3u) * NN);
        key[q*4+1] = (unsigned short)((unsigned)d4.y - (sm1 & ~3u) * NN);
        key[q*4+2] = (unsigned short)((unsigned)d4.z - (sm2 & ~3u) * NN);
        key[q*4+3] = (unsigned short)((unsigned)d4.w - (sm3 & ~3u) * NN);
        vv[q*4+0] = x0 * w4.x; vv[q*4+1] = x1 * w4.y;
        vv[q*4+2] = x2 * w4.z; vv[q*4+3] = x3 * w4.w;
        rk[q*4+0] = (unsigned short)r0; rk[q*4+1] = (unsigned short)r1;
        rk[q*4+2] = (unsigned short)r2; rk[q*4+3] = (unsigned short)r3;
        bk[q*4+0] = (unsigned char)g0; bk[q*4+1] = (unsigned char)g1;
        bk[q*4+2] = (unsigned char)g2; bk[q*4+3] = (unsigned char)g3;
    }
    __syncthreads();

    // exclusive scan of hist[64] within the first wave
    if (t < NBG) {
        unsigned h = hist[t], v = h;
        #pragma unroll
        for (int off = 1; off < 64; off <<= 1) {
            unsigned u = __shfl_up(v, off);
            if (t >= off) v += u;
        }
        start[t] = v - h;
        stab[blockIdx.x * NBG + t] = (unsigned short)(v - h);
    }
    __syncthreads();

    // direct scatter to the block-private 32 KB region (L2 merges the 8B writes)
    uint2* rb = recs + (size_t)blockIdx.x * EPB;
    #pragma unroll
    for (int e = 0; e < EPT; ++e)
        rb[start[bk[e]] + (unsigned)rk[e]] =
            make_uint2((unsigned)key[e], __float_as_uint(vv[e]));
}

// ===== PASS 2a: gather-free grouped replay (4 samples / 35KB LDS, 512B runs) =====
__global__ __launch_bounds__(512, 8)
void k_replay7(const uint2* __restrict__ recs, const unsigned short* __restrict__ stab,
               float* __restrict__ paggr)
{
    __shared__ float acc[GNN];                  // 35,312 B
    const int t = threadIdx.x;
    const int g = blockIdx.x & (NBG - 1);       // bucket group (64)
    const int r = blockIdx.x >> 6;              // split 0..RSPL-1
    for (int n = t; n < GNN; n += 512) acc[n] = 0.f;
    __syncthreads();

    const int lane = t & 63, w = t >> 6;        // 8 waves
    const int nreg = NBLK / RSPL;               // 256 regions per block
    int region = r * nreg + w;

    unsigned s0n = stab[(size_t)region * NBG + g];
    unsigned s1n = (g < NBG-1) ? (unsigned)stab[(size_t)region * NBG + g + 1]
                               : (unsigned)EPB;
    for (int ri = w; ri < nreg; ri += 8) {
        const unsigned b0 = s0n, b1 = s1n;
        const uint2* rp = recs + (size_t)region * EPB;
        const int regionN = region + 8;
        if (ri + 8 < nreg) {
            s0n = stab[(size_t)regionN * NBG + g];
            s1n = (g < NBG-1) ? (unsigned)stab[(size_t)regionN * NBG + g + 1]
                              : (unsigned)EPB;
        }
        for (unsigned u = b0 + (unsigned)lane; u < b1; u += 64u) {
            uint2 rec = rp[u];
            atomicAdd(&acc[rec.x], __uint_as_float(rec.y));
        }
        region = regionN;
    }
    __syncthreads();
    float* pa = paggr + ((size_t)r * NBG + g) * GNN;
    for (int n = t; n < GNN; n += 512) pa[n] = acc[n];
}

// ===== PASS 2b: sum partials + relu/LN/conv1/bn/conv2/bn -> z =====
__global__ __launch_bounds__(512)
void k_ln_conv(const float* __restrict__ x, const float* __restrict__ paggr,
              const float* __restrict__ w_root, const float* __restrict__ w_rel,
              const float* __restrict__ b_rel,
              const float* __restrict__ ln_g, const float* __restrict__ ln_b,
              const float* __restrict__ gc1_w, const float* __restrict__ gc1_b,
              const float* __restrict__ bn1_g, const float* __restrict__ bn1_b,
              const float* __restrict__ gc2_w, const float* __restrict__ gc2_b,
              const float* __restrict__ bn2_g, const float* __restrict__ bn2_b,
              float* __restrict__ z)
{
    __shared__ float xs[NN], acc[NN];
    __shared__ float gw1[CC1*MM], gb1[CC1], sb1[CC1], tb1[CC1];
    __shared__ float gw2[CC2*CC1], gb2[CC2], sb2[CC2], tb2[CC2];
    __shared__ float redS[8], redQ[8];
    __shared__ float s_mu, s_rs;

    const int b = blockIdx.x, t = threadIdx.x;
    const float* xb = x + b*NN;
    const float* pb = paggr + ((size_t)(b >> 2)) * GNN + (size_t)(b & 3) * NN;
    const size_t rstride = (size_t)NBG * GNN;
    for (int n = t; n < NN; n += 512) {
        xs[n] = xb[n];
        float a = 0.f;
        #pragma unroll
        for (int r = 0; r < RSPL; ++r)
            a += pb[(size_t)r * rstride + n];
        acc[n] = a;
    }
    if (t < CC1*MM) gw1[t] = gc1_w[t];
    if (t >= 192 && t < 192+CC1) { int o = t-192; gb1[o]=gc1_b[o]; sb1[o]=BN_SCALE*bn1_g[o]; tb1[o]=bn1_b[o]; }
    if (t >= 208 && t < 208+CC2*CC1) gw2[t-208] = gc2_w[t-208];
    if (t >= 240 && t < 240+CC2) { int p=t-240; gb2[p]=gc2_b[p]; sb2[p]=BN_SCALE*bn2_g[p]; tb2[p]=bn2_b[p]; }

    float wr[MM], br[MM], wo[MM];
    #pragma unroll
    for (int m = 0; m < MM; ++m) { wr[m]=w_rel[m]; br[m]=b_rel[m]; wo[m]=w_root[m]; }
    __syncthreads();

    float S = 0.f, Q = 0.f;
    for (int n = t; n < NN; n += 512) {
        float a = acc[n], xv = xs[n];
        #pragma unroll
        for (int m = 0; m < MM; ++m) {
            float h = fmaxf(fmaf(a, wr[m], fmaf(xv, wo[m], br[m])), 0.f);
            S += h; Q += h*h;
        }
    }
    #pragma unroll
    for (int off = 32; off; off >>= 1) { S += __shfl_down(S, off); Q += __shfl_down(Q, off); }
    if ((t & 63) == 0) { redS[t>>6] = S; redQ[t>>6] = Q; }
    __syncthreads();
    if (t == 0) {
        float SS = 0.f, QQ = 0.f;
        #pragma unroll
        for (int i = 0; i < 8; ++i) { SS += redS[i]; QQ += redQ[i]; }
        const float inv = 1.f / (float)(NN*MM);
        float mu = SS * inv;
        float var = QQ * inv - mu*mu;
        s_mu = mu; s_rs = rsqrtf(var + LN_EPS);
    }
    __syncthreads();
    const float mu = s_mu, rs = s_rs;

    float* zb = z + (size_t)b * KK1;
    for (int n = t; n < NN; n += 512) {
        float a = acc[n], xv = xs[n];
        float hn[MM];
        const float4* g4  = reinterpret_cast<const float4*>(ln_g + n*MM);
        const float4* be4 = reinterpret_cast<const float4*>(ln_b + n*MM);
        #pragma unroll
        for (int q = 0; q < 4; ++q) {
            float4 g = g4[q], be = be4[q];
            float gg[4]  = {g.x, g.y, g.z, g.w};
            float bb_[4] = {be.x, be.y, be.z, be.w};
            #pragma unroll
            for (int j = 0; j < 4; ++j) {
                int m = q*4 + j;
                float h = fmaxf(fmaf(a, wr[m], fmaf(xv, wo[m], br[m])), 0.f);
                hn[m] = (h - mu) * rs * gg[j] + bb_[j];
            }
        }
        float y1[CC1];
        #pragma unroll
        for (int o = 0; o < CC1; ++o) {
            float a1 = gb1[o];
            #pragma unroll
            for (int m = 0; m < MM; ++m) a1 = fmaf(gw1[o*MM+m], hn[m], a1);
            y1[o] = fmaxf(a1, 0.f) * sb1[o] + tb1[o];
        }
        #pragma unroll
        for (int p = 0; p < CC2; ++p) {
            float a2 = gb2[p];
            #pragma unroll
            for (int o = 0; o < CC1; ++o) a2 = fmaf(gw2[p*CC1+o], y1[o], a2);
            zb[p*NN + n] = fmaxf(a2, 0.f) * sb2[p] + tb2[p];
        }
    }
}

// ------------- FC1 GEMM: split-K partials (no atomics) -------------
#define GK_CHUNK 288   /* grid.z = 31; 31*288 = 8928 >= 8828 */
__global__ __launch_bounds__(256)
void k_fc1_part(const float* __restrict__ z, const float* __restrict__ W1,
                float* __restrict__ out1_part)
{
    __shared__ float zs[64*36];
    __shared__ float ws_[32*68];
    const int bt = blockIdx.x, jt = blockIdx.y, ks = blockIdx.z;
    const int t = threadIdx.x;
    const int tb = t >> 4, tj = t & 15;
    const int k0 = ks * GK_CHUNK;
    const int kend = min(k0 + GK_CHUNK, KK1);
    float acc[4][4] = {};
    const int zrow = t >> 2, zcol = (t & 3) * 8;
    const int wrow = t >> 3, wcol = (t & 7) * 8;

    for (int kc = k0; kc < kend; kc += 32) {
        const float* zsrc = z + (size_t)(bt*64 + zrow)*KK1 + kc + zcol;
        #pragma unroll
        for (int q = 0; q < 2; ++q) {
            int k = kc + zcol + q*4;
            float4 v;
            if (k + 3 < kend) v = *reinterpret_cast<const float4*>(zsrc + q*4);
            else {
                v.x = (k+0 < kend) ? zsrc[q*4+0] : 0.f;
                v.y = (k+1 < kend) ? zsrc[q*4+1] : 0.f;
                v.z = (k+2 < kend) ? zsrc[q*4+2] : 0.f;
                v.w = (k+3 < kend) ? zsrc[q*4+3] : 0.f;
            }
            *reinterpret_cast<float4*>(&zs[zrow*36 + zcol + q*4]) = v;
        }
        {
            int k = kc + wrow;
            const float* wsrc = W1 + (size_t)k*HH1 + jt*64 + wcol;
            #pragma unroll
            for (int q = 0; q < 2; ++q) {
                float4 v;
                if (k < kend) v = *reinterpret_cast<const float4*>(wsrc + q*4);
                else v = float4{0.f,0.f,0.f,0.f};
                *reinterpret_cast<float4*>(&ws_[wrow*68 + wcol + q*4]) = v;
            }
        }
        __syncthreads();
        #pragma unroll
        for (int kk = 0; kk < 32; ++kk) {
            float4 w4 = *reinterpret_cast<const float4*>(&ws_[kk*68 + tj*4]);
            float zv[4], wv[4] = {w4.x, w4.y, w4.z, w4.w};
            #pragma unroll
            for (int ib = 0; ib < 4; ++ib) zv[ib] = zs[(tb*4+ib)*36 + kk];
            #pragma unroll
            for (int ib = 0; ib < 4; ++ib)
                #pragma unroll
                for (int ij = 0; ij < 4; ++ij)
                    acc[ib][ij] = fmaf(zv[ib], wv[ij], acc[ib][ij]);
        }
        __syncthreads();
    }
    #pragma unroll
    for (int ib = 0; ib < 4; ++ib) {
        int row = bt*64 + tb*4 + ib;
        float4 v = make_float4(acc[ib][0], acc[ib][1], acc[ib][2], acc[ib][3]);
        *reinterpret_cast<float4*>(
            &out1_part[((size_t)ks*256 + row)*HH1 + jt*64 + tj*4]) = v;
    }
}

// ------------- tail: sum partials -> bn-relu -> FC2 -> bn-relu -> dot -------------
__global__ __launch_bounds__(256)
void k_tail_part(const float* __restrict__ out1_part,
            const float* __restrict__ fc_b1, const float* __restrict__ fbn1_g,
            const float* __restrict__ fbn1_b,
            const float* __restrict__ W2, const float* __restrict__ fc_b2,
            const float* __restrict__ fbn2_g, const float* __restrict__ fbn2_b,
            const float* __restrict__ fc1_w, const float* __restrict__ fc1_b,
            float* __restrict__ out)
{
    __shared__ float o1s[HH1];
    const int b = blockIdx.x, t = threadIdx.x;
    float raw = fc_b1[t];
    #pragma unroll 4
    for (int ks = 0; ks < 31; ++ks)
        raw += out1_part[((size_t)ks*256 + b)*HH1 + t];
    o1s[t] = fmaxf(raw * (BN_SCALE * fbn1_g[t]) + fbn1_b[t], 0.f);
    __syncthreads();
    if (t < HH2) {
        float acc = fc_b2[t];
        #pragma unroll 4
        for (int j = 0; j < HH1; ++j) acc = fmaf(o1s[j], W2[j*HH2 + t], acc);
        float v2 = fmaxf(acc * (BN_SCALE * fbn2_g[t]) + fbn2_b[t], 0.f);
        float c = v2 * fc1_w[t];
        #pragma unroll
        for (int off = 32; off; off >>= 1) c += __shfl_down(c, off);
        if (t == 0) out[b] = c + fc1_b[0];
    }
}

// =================== fallback path (round-1, proven; used if ws too small) ===================
__global__ __launch_bounds__(256)
void k_edge(const int* __restrict__ src, const int* __restrict__ dst,
            const float* __restrict__ ew, const float* __restrict__ x,
            float* __restrict__ agg)
{
    int i = blockIdx.x * 256 + threadIdx.x;
    const int4   s4 = reinterpret_cast<const int4*>(src)[i];
    const int4   d4 = reinterpret_cast<const int4*>(dst)[i];
    const float4 w4 = reinterpret_cast<const float4*>(ew)[i];
    unsafeAtomicAdd(&agg[d4.x], x[s4.x] * w4.x);
    unsafeAtomicAdd(&agg[d4.y], x[s4.y] * w4.y);
    unsafeAtomicAdd(&agg[d4.z], x[s4.z] * w4.z);
    unsafeAtomicAdd(&agg[d4.w], x[s4.w] * w4.w);
}

__global__ __launch_bounds__(256)
void k_sample(const float* __restrict__ x, const float* __restrict__ agg,
              const float* __restrict__ w_root, const float* __restrict__ w_rel,
              const float* __restrict__ b_rel,
              const float* __restrict__ ln_g, const float* __restrict__ ln_b,
              const float* __restrict__ gc1_w, const float* __restrict__ gc1_b,
              const float* __restrict__ bn1_g, const float* __restrict__ bn1_b,
              const float* __restrict__ gc2_w, const float* __restrict__ gc2_b,
              const float* __restrict__ bn2_g, const float* __restrict__ bn2_b,
              float* __restrict__ z)
{
    __shared__ float xs[NN], as[NN];
    __shared__ float gw1[CC1*MM], gb1[CC1], sb1[CC1], tb1[CC1];
    __shared__ float gw2[CC2*CC1], gb2[CC2], sb2[CC2], tb2[CC2];
    __shared__ float redS[4], redQ[4];
    __shared__ float s_mu, s_rs;

    const int b = blockIdx.x, t = threadIdx.x;
    const float* xb = x + b*NN;
    const float* ab = agg + b*NN;
    for (int n = t; n < NN; n += 256) { xs[n] = xb[n]; as[n] = ab[n]; }
    if (t < CC1*MM) gw1[t] = gc1_w[t];
    if (t >= 192 && t < 192+CC1) { int o = t-192; gb1[o]=gc1_b[o]; sb1[o]=BN_SCALE*bn1_g[o]; tb1[o]=bn1_b[o]; }
    if (t >= 208 && t < 208+CC2*CC1) gw2[t-208] = gc2_w[t-208];
    if (t >= 240 && t < 240+CC2) { int p=t-240; gb2[p]=gc2_b[p]; sb2[p]=BN_SCALE*bn2_g[p]; tb2[p]=bn2_b[p]; }

    float wr[MM], br[MM], wo[MM];
    #pragma unroll
    for (int m = 0; m < MM; ++m) { wr[m]=w_rel[m]; br[m]=b_rel[m]; wo[m]=w_root[m]; }
    __syncthreads();

    float S = 0.f, Q = 0.f;
    for (int n = t; n < NN; n += 256) {
        float a = as[n], xv = xs[n];
        #pragma unroll
        for (int m = 0; m < MM; ++m) {
            float h = fmaxf(fmaf(a, wr[m], fmaf(xv, wo[m], br[m])), 0.f);
            S += h; Q += h*h;
        }
    }
    #pragma unroll
    for (int off = 32; off; off >>= 1) { S += __shfl_down(S, off); Q += __shfl_down(Q, off); }
    if ((t & 63) == 0) { redS[t>>6] = S; redQ[t>>6] = Q; }
    __syncthreads();
    if (t == 0) {
        float SS = redS[0]+redS[1]+redS[2]+redS[3];
        float QQ = redQ[0]+redQ[1]+redQ[2]+redQ[3];
        const float inv = 1.f / (float)(NN*MM);
        float mu = SS * inv;
        float var = QQ * inv - mu*mu;
        s_mu = mu; s_rs = rsqrtf(var + LN_EPS);
    }
    __syncthreads();
    const float mu = s_mu, rs = s_rs;

    float* zb = z + (size_t)b * KK1;
    for (int n = t; n < NN; n += 256) {
        float a = as[n], xv = xs[n];
        float hn[MM];
        const float4* g4  = reinterpret_cast<const float4*>(ln_g + n*MM);
        const float4* be4 = reinterpret_cast<const float4*>(ln_b + n*MM);
        #pragma unroll
        for (int q = 0; q < 4; ++q) {
            float4 g = g4[q], be = be4[q];
            float gg[4]  = {g.x, g.y, g.z, g.w};
            float bb_[4] = {be.x, be.y, be.z, be.w};
            #pragma unroll
            for (int j = 0; j < 4; ++j) {
                int m = q*4 + j;
                float h = fmaxf(fmaf(a, wr[m], fmaf(xv, wo[m], br[m])), 0.f);
                hn[m] = (h - mu) * rs * gg[j] + bb_[j];
            }
        }
        float y1[CC1];
        #pragma unroll
        for (int o = 0; o < CC1; ++o) {
            float a1 = gb1[o];
            #pragma unroll
            for (int m = 0; m < MM; ++m) a1 = fmaf(gw1[o*MM+m], hn[m], a1);
            y1[o] = fmaxf(a1, 0.f) * sb1[o] + tb1[o];
        }
        #pragma unroll
        for (int p = 0; p < CC2; ++p) {
            float a2 = gb2[p];
            #pragma unroll
            for (int o = 0; o < CC1; ++o) a2 = fmaf(gw2[p*CC1+o], y1[o], a2);
            zb[p*NN + n] = fmaxf(a2, 0.f) * sb2[p] + tb2[p];
        }
    }
}

__global__ __launch_bounds__(256)
void k_fc1(const float* __restrict__ z, const float* __restrict__ W1,
           float* __restrict__ out1_raw)
{
    __shared__ float zs[64*36];
    __shared__ float ws_[32*68];
    const int bt = blockIdx.x, jt = blockIdx.y, ks = blockIdx.z;
    const int t = threadIdx.x;
    const int tb = t >> 4, tj = t & 15;
    const int k0 = ks * GK_CHUNK;
    const int kend = min(k0 + GK_CHUNK, KK1);
    float acc[4][4] = {};
    const int zrow = t >> 2, zcol = (t & 3) * 8;
    const int wrow = t >> 3, wcol = (t & 7) * 8;

    for (int kc = k0; kc < kend; kc += 32) {
        const float* zsrc = z + (size_t)(bt*64 + zrow)*KK1 + kc + zcol;
        #pragma unroll
        for (int q = 0; q < 2; ++q) {
            int k = kc + zcol + q*4;
            float4 v;
            if (k + 3 < kend) v = *reinterpret_cast<const float4*>(zsrc + q*4);
            else {
                v.x = (k+0 < kend) ? zsrc[q*4+0] : 0.f;
                v.y = (k+1 < kend) ? zsrc[q*4+1] : 0.f;
                v.z = (k+2 < kend) ? zsrc[q*4+2] : 0.f;
                v.w = (k+3 < kend) ? zsrc[q*4+3] : 0.f;
            }
            *reinterpret_cast<float4*>(&zs[zrow*36 + zcol + q*4]) = v;
        }
        {
            int k = kc + wrow;
            const float* wsrc = W1 + (size_t)k*HH1 + jt*64 + wcol;
            #pragma unroll
            for (int q = 0; q < 2; ++q) {
                float4 v;
                if (k < kend) v = *reinterpret_cast<const float4*>(wsrc + q*4);
                else v = float4{0.f,0.f,0.f,0.f};
                *reinterpret_cast<float4*>(&ws_[wrow*68 + wcol + q*4]) = v;
            }
        }
        __syncthreads();
        #pragma unroll
        for (int kk = 0; kk < 32; ++kk) {
            float4 w4 = *reinterpret_cast<const float4*>(&ws_[kk*68 + tj*4]);
            float zv[4], wv[4] = {w4.x, w4.y, w4.z, w4.w};
            #pragma unroll
            for (int ib = 0; ib < 4; ++ib) zv[ib] = zs[(tb*4+ib)*36 + kk];
            #pragma unroll
            for (int ib = 0; ib < 4; ++ib)
                #pragma unroll
                for (int ij = 0; ij < 4; ++ij)
                    acc[ib][ij] = fmaf(zv[ib], wv[ij], acc[ib][ij]);
        }
        __syncthreads();
    }
    #pragma unroll
    for (int ib = 0; ib < 4; ++ib) {
        int row = bt*64 + tb*4 + ib;
        #pragma unroll
        for (int ij = 0; ij < 4; ++ij)
            unsafeAtomicAdd(&out1_raw[row*HH1 + jt*64 + tj*4 + ij], acc[ib][ij]);
    }
}

__global__ __launch_bounds__(256)
void k_tail(const float* __restrict__ out1_raw,
            const float* __restrict__ fc_b1, const float* __restrict__ fbn1_g,
            const float* __restrict__ fbn1_b,
            const float* __restrict__ W2, const float* __restrict__ fc_b2,
            const float* __restrict__ fbn2_g, const float* __restrict__ fbn2_b,
            const float* __restrict__ fc1_w, const float* __restrict__ fc1_b,
            float* __restrict__ out)
{
    __shared__ float o1s[HH1];
    const int b = blockIdx.x, t = threadIdx.x;
    float raw = out1_raw[b*HH1 + t] + fc_b1[t];
    o1s[t] = fmaxf(raw * (BN_SCALE * fbn1_g[t]) + fbn1_b[t], 0.f);
    __syncthreads();
    if (t < HH2) {
        float acc = fc_b2[t];
        #pragma unroll 4
        for (int j = 0; j < HH1; ++j) acc = fmaf(o1s[j], W2[j*HH2 + t], acc);
        float v2 = fmaxf(acc * (BN_SCALE * fbn2_g[t]) + fbn2_b[t], 0.f);
        float c = v2 * fc1_w[t];
        #pragma unroll
        for (int off = 32; off; off >>= 1) c += __shfl_down(c, off);
        if (t == 0) out[b] = c + fc1_b[0];
    }
}

extern "C" void kernel_launch(void* const* d_in, const int* in_sizes, int n_in,
                              void* d_out, int out_size, void* d_ws, size_t ws_size,
                              hipStream_t stream)
{
    const float* x      = (const float*)d_in[0];
    const int*   ei     = (const int*)  d_in[1];
    const float* ew     = (const float*)d_in[2];
    const float* w_root = (const float*)d_in[3];
    const float* w_rel  = (const float*)d_in[4];
    const float* b_rel  = (const float*)d_in[5];
    const float* ln_g   = (const float*)d_in[6];
    const float* ln_b   = (const float*)d_in[7];
    const float* gc1_w  = (const float*)d_in[8];
    const float* gc1_b  = (const float*)d_in[9];
    const float* bn1_g  = (const float*)d_in[10];
    const float* bn1_b  = (const float*)d_in[11];
    const float* gc2_w  = (const float*)d_in[12];
    const float* gc2_b  = (const float*)d_in[13];
    const float* bn2_g  = (const float*)d_in[14];
    const float* bn2_b  = (const float*)d_in[15];
    const float* fc_w1  = (const float*)d_in[16];
    const float* fc_b1  = (const float*)d_in[17];
    const float* fbn1_g = (const float*)d_in[18];
    const float* fbn1_b = (const float*)d_in[19];
    const float* fc_w2  = (const float*)d_in[20];
    const float* fc_b2  = (const float*)d_in[21];
    const float* fbn2_g = (const float*)d_in[22];
    const float* fbn2_b = (const float*)d_in[23];
    const float* fc1_w  = (const float*)d_in[24];
    const float* fc1_b  = (const float*)d_in[25];
    float* out = (float*)d_out;

    char* ws = (char*)d_ws;
    // layout: recs | stab | paggr (reused as o1p) | zbuf   = 180.0 MB
    const size_t off_recs  = 0;                                   // 134,217,728
    const size_t off_stab  = off_recs + (size_t)NBLK*EPB*8;       // +524,288
    const size_t off_paggr = off_stab + (size_t)NBLK*NBG*2;
    const size_t sz_paggr  = (size_t)RSPL*NBG*GNN*4;              // 36,175,872
    const size_t off_zbuf  = off_paggr + sz_paggr;
    const size_t need      = off_zbuf + (size_t)BB*KK1*4;         // 179,957,760

    if (ws_size >= need) {
        uint2*          recs  = (uint2*)(ws + off_recs);
        unsigned short* stab  = (unsigned short*)(ws + off_stab);
        float*          paggr = (float*)(ws + off_paggr);
        float*          zbuf  = (float*)(ws + off_zbuf);
        float*          o1p   = (float*)(ws + off_paggr);  // reused after k_ln_conv

        k_place5<<<NBLK, TPB, 0, stream>>>(ei, ei + EE, ew, x, recs, stab);
        k_replay7<<<NBG*RSPL, 512, 0, stream>>>(recs, stab, paggr);
        k_ln_conv<<<BB, 512, 0, stream>>>(x, paggr,
                                         w_root, w_rel, b_rel, ln_g, ln_b,
                                         gc1_w, gc1_b, bn1_g, bn1_b,
                                         gc2_w, gc2_b, bn2_g, bn2_b, zbuf);
        k_fc1_part<<<dim3(4,4,31), 256, 0, stream>>>(zbuf, fc_w1, o1p);
        k_tail_part<<<BB, 256, 0, stream>>>(o1p, fc_b1, fbn1_g, fbn1_b,
                                       fc_w2, fc_b2, fbn2_g, fbn2_b,
                                       fc1_w, fc1_b, out);
    } else {
        // round-1 fallback (proven <= 11.6 MB ws)
        float* agg      = (float*)(ws);
        float* zbuf     = (float*)(ws + 2259968);
        float* out1_raw = (float*)(ws + 2259968 + 9039872);

        hipMemsetAsync(agg,      0, (size_t)BB*NN*sizeof(float),  stream);
        hipMemsetAsync(out1_raw, 0, (size_t)BB*HH1*sizeof(float), stream);

        k_edge<<<EE/4/256, 256, 0, stream>>>(ei, ei + EE, ew, x, agg);
        k_sample<<<BB, 256, 0, stream>>>(x, agg, w_root, w_rel, b_rel, ln_g, ln_b,
                                         gc1_w, gc1_b, bn1_g, bn1_b,
                                         gc2_w, gc2_b, bn2_g, bn2_b, zbuf);
        k_fc1<<<dim3(4,4,31), 256, 0, stream>>>(zbuf, fc_w1, out1_raw);
        k_tail<<<BB, 256, 0, stream>>>(out1_raw, fc_b1, fbn1_g, fbn1_b,
                                       fc_w2, fc_b2, fbn2_g, fbn2_b,
                                       fc1_w, fc1_b, out);
    }
}

// Round 14
// 309.338 us; speedup vs baseline: 1.1262x; 1.1262x over previous
//
#include <hip/hip_runtime.h>
#include <hip/hip_bf16.h>

#define BB   256
#define NN   2207
#define MM   16
#define EE   16777216
#define CC1  12
#define CC2  4
#define HH1  256
#define HH2  64
#define KK1  (CC2*NN)          /* 8828 */
#define LN_EPS 1e-5f
#define BN_SCALE 0.9999950000374997f   /* 1/sqrt(1+1e-5) */
#define NBK  256               /* buckets == samples */
#define MAGIC 1946067ull       /* ceil(2^32/2207), exact for d < 564992 */
#define EPB  4096              /* edges per bin block */
#define TPB  512
#define EPT  (EPB/TPB)         /* 8 edges per thread */
#define NBLK (EE/EPB)          /* 4096 bin blocks */
#define GRP  4                 /* samples per replay group */
#define NGRP (NBK/GRP)         /* 64 groups */
#define RSP6 16                /* replay splits; regions/block = 256 */

static __device__ __forceinline__ unsigned bucket_of(int d) {
    return (unsigned)(((unsigned long long)(unsigned)d * MAGIC) >> 32);
}

// ===== PASS 1: rank + scan + direct scatter to block-private regions (round-10 proven) =====
// record = ( src<<12 | dst_local , w )  -- gather deferred to replay
__global__ __launch_bounds__(TPB, 8)
void k_place4(const int* __restrict__ src, const int* __restrict__ dst,
              const float* __restrict__ ew,
              uint2* __restrict__ recs, unsigned short* __restrict__ stab)
{
    __shared__ unsigned int hist[NBK], start[NBK];
    __shared__ unsigned int wtot[4];

    const int t = threadIdx.x;
    if (t < NBK) hist[t] = 0;
    __syncthreads();

    const int i4base = blockIdx.x * (EPB/4);
    unsigned key[EPT];
    float    wv[EPT];
    unsigned short rk[EPT];
    unsigned char  bk[EPT];
    #pragma unroll
    for (int q = 0; q < EPT/4; ++q) {
        int i4 = i4base + q*TPB + t;
        int4   s4 = reinterpret_cast<const int4*>(src)[i4];
        int4   d4 = reinterpret_cast<const int4*>(dst)[i4];
        float4 w4 = reinterpret_cast<const float4*>(ew)[i4];
        unsigned b0 = bucket_of(d4.x), b1 = bucket_of(d4.y);
        unsigned b2 = bucket_of(d4.z), b3 = bucket_of(d4.w);
        unsigned r0 = atomicAdd(&hist[b0], 1u);
        unsigned r1 = atomicAdd(&hist[b1], 1u);
        unsigned r2 = atomicAdd(&hist[b2], 1u);
        unsigned r3 = atomicAdd(&hist[b3], 1u);
        key[q*4+0] = ((unsigned)s4.x << 12) | (unsigned)(d4.x - (int)(b0*NN));
        key[q*4+1] = ((unsigned)s4.y << 12) | (unsigned)(d4.y - (int)(b1*NN));
        key[q*4+2] = ((unsigned)s4.z << 12) | (unsigned)(d4.z - (int)(b2*NN));
        key[q*4+3] = ((unsigned)s4.w << 12) | (unsigned)(d4.w - (int)(b3*NN));
        wv[q*4+0] = w4.x; wv[q*4+1] = w4.y; wv[q*4+2] = w4.z; wv[q*4+3] = w4.w;
        rk[q*4+0] = (unsigned short)r0; rk[q*4+1] = (unsigned short)r1;
        rk[q*4+2] = (unsigned short)r2; rk[q*4+3] = (unsigned short)r3;
        bk[q*4+0] = (unsigned char)b0; bk[q*4+1] = (unsigned char)b1;
        bk[q*4+2] = (unsigned char)b2; bk[q*4+3] = (unsigned char)b3;
    }
    __syncthreads();

    // exclusive prefix scan of hist[256] (4 waves of 64)
    if (t < NBK) {
        unsigned h = hist[t], v = h;
        #pragma unroll
        for (int off = 1; off < 64; off <<= 1) {
            unsigned u = __shfl_up(v, off);
            if ((t & 63) >= off) v += u;
        }
        start[t] = v - h;
        if ((t & 63) == 63) wtot[t >> 6] = v;
    }
    __syncthreads();
    if (t < NBK) {
        const int w = t >> 6;
        unsigned wo = 0;
        if (w > 0) wo += wtot[0];
        if (w > 1) wo += wtot[1];
        if (w > 2) wo += wtot[2];
        start[t] += wo;
        stab[blockIdx.x * NBK + t] = (unsigned short)(start[t]);
    }
    __syncthreads();

    uint2* rb = recs + (size_t)blockIdx.x * EPB;
    #pragma unroll
    for (int e = 0; e < EPT; ++e)
        rb[start[bk[e]] + (unsigned)rk[e]] =
            make_uint2(key[e], __float_as_uint(wv[e]));
}

// ===== PASS 2a: sample-GROUP replay, LDS fadd via unsafeAtomicAdd (ds_add_f32) =====
__global__ __launch_bounds__(512, 8)
void k_replay6(const uint2* __restrict__ recs, const unsigned short* __restrict__ stab,
               const float* __restrict__ x, float* __restrict__ paggr)
{
    __shared__ float acc[GRP*NN];               // 35,312 B
    const int t = threadIdx.x;
    const int g = blockIdx.x & (NGRP - 1);      // sample group (64)
    const int r = blockIdx.x >> 6;              // split 0..RSP6-1
    for (int n = t; n < GRP*NN; n += 512) acc[n] = 0.f;
    __syncthreads();

    const int lane = t & 63, w = t >> 6;        // 8 waves
    const int nreg = NBLK / RSP6;               // 256 regions per block
    const int reg0 = r * nreg;
    const int j0 = g * GRP;

    // first region bounds prefetch
    int region = reg0 + w;
    const unsigned short* sb = stab + (size_t)region * NBK + j0;
    unsigned c0 = sb[0], c1 = sb[1], c2 = sb[2], c3 = sb[3];
    unsigned c4 = (j0 + GRP < NBK) ? (unsigned)sb[4] : (unsigned)EPB;

    for (int ri = w; ri < nreg; ri += 8) {
        const unsigned b0 = c0, b1 = c1, b2 = c2, b3 = c3, b4 = c4;
        const uint2* rp = recs + (size_t)region * EPB;
        const int regionN = region + 8;
        if (ri + 8 < nreg) {                    // prefetch next region's bounds
            const unsigned short* sbn = stab + (size_t)regionN * NBK + j0;
            c0 = sbn[0]; c1 = sbn[1]; c2 = sbn[2]; c3 = sbn[3];
            c4 = (j0 + GRP < NBK) ? (unsigned)sbn[4] : (unsigned)EPB;
        }
        for (unsigned u = b0 + (unsigned)lane; u < b4; u += 64u) {
            uint2 rec = rp[u];
            unsigned so = (u >= b1) + (u >= b2) + (u >= b3);
            unsafeAtomicAdd(&acc[so * NN + (rec.x & 0xFFFu)],
                            x[rec.x >> 12] * __uint_as_float(rec.y));
        }
        region = regionN;
    }
    __syncthreads();
    float* pa = paggr + (((size_t)r * NGRP + g) * GRP) * NN;
    for (int n = t; n < GRP*NN; n += 512) pa[n] = acc[n];
}

// ===== PASS 2b: sum partials + relu/LN/conv1/bn/conv2/bn -> z =====
__global__ __launch_bounds__(512)
void k_ln_conv(const float* __restrict__ x, const float* __restrict__ paggr,
              const float* __restrict__ w_root, const float* __restrict__ w_rel,
              const float* __restrict__ b_rel,
              const float* __restrict__ ln_g, const float* __restrict__ ln_b,
              const float* __restrict__ gc1_w, const float* __restrict__ gc1_b,
              const float* __restrict__ bn1_g, const float* __restrict__ bn1_b,
              const float* __restrict__ gc2_w, const float* __restrict__ gc2_b,
              const float* __restrict__ bn2_g, const float* __restrict__ bn2_b,
              float* __restrict__ z)
{
    __shared__ float xs[NN], acc[NN];
    __shared__ float gw1[CC1*MM], gb1[CC1], sb1[CC1], tb1[CC1];
    __shared__ float gw2[CC2*CC1], gb2[CC2], sb2[CC2], tb2[CC2];
    __shared__ float redS[8], redQ[8];
    __shared__ float s_mu, s_rs;

    const int b = blockIdx.x, t = threadIdx.x;
    const float* xb = x + b*NN;
    const float* pb = paggr + (((size_t)(b >> 2)) * GRP + (b & 3)) * NN;
    const size_t rstride = (size_t)NGRP * GRP * NN;
    for (int n = t; n < NN; n += 512) {
        xs[n] = xb[n];
        float a = 0.f;
        #pragma unroll
        for (int r = 0; r < RSP6; ++r)
            a += pb[(size_t)r * rstride + n];
        acc[n] = a;
    }
    if (t < CC1*MM) gw1[t] = gc1_w[t];
    if (t >= 192 && t < 192+CC1) { int o = t-192; gb1[o]=gc1_b[o]; sb1[o]=BN_SCALE*bn1_g[o]; tb1[o]=bn1_b[o]; }
    if (t >= 208 && t < 208+CC2*CC1) gw2[t-208] = gc2_w[t-208];
    if (t >= 240 && t < 240+CC2) { int p=t-240; gb2[p]=gc2_b[p]; sb2[p]=BN_SCALE*bn2_g[p]; tb2[p]=bn2_b[p]; }

    float wr[MM], br[MM], wo[MM];
    #pragma unroll
    for (int m = 0; m < MM; ++m) { wr[m]=w_rel[m]; br[m]=b_rel[m]; wo[m]=w_root[m]; }
    __syncthreads();

    float S = 0.f, Q = 0.f;
    for (int n = t; n < NN; n += 512) {
        float a = acc[n], xv = xs[n];
        #pragma unroll
        for (int m = 0; m < MM; ++m) {
            float h = fmaxf(fmaf(a, wr[m], fmaf(xv, wo[m], br[m])), 0.f);
            S += h; Q += h*h;
        }
    }
    #pragma unroll
    for (int off = 32; off; off >>= 1) { S += __shfl_down(S, off); Q += __shfl_down(Q, off); }
    if ((t & 63) == 0) { redS[t>>6] = S; redQ[t>>6] = Q; }
    __syncthreads();
    if (t == 0) {
        float SS = 0.f, QQ = 0.f;
        #pragma unroll
        for (int i = 0; i < 8; ++i) { SS += redS[i]; QQ += redQ[i]; }
        const float inv = 1.f / (float)(NN*MM);
        float mu = SS * inv;
        float var = QQ * inv - mu*mu;
        s_mu = mu; s_rs = rsqrtf(var + LN_EPS);
    }
    __syncthreads();
    const float mu = s_mu, rs = s_rs;

    float* zb = z + (size_t)b * KK1;
    for (int n = t; n < NN; n += 512) {
        float a = acc[n], xv = xs[n];
        float hn[MM];
        const float4* g4  = reinterpret_cast<const float4*>(ln_g + n*MM);
        const float4* be4 = reinterpret_cast<const float4*>(ln_b + n*MM);
        #pragma unroll
        for (int q = 0; q < 4; ++q) {
            float4 g = g4[q], be = be4[q];
            float gg[4]  = {g.x, g.y, g.z, g.w};
            float bb_[4] = {be.x, be.y, be.z, be.w};
            #pragma unroll
            for (int j = 0; j < 4; ++j) {
                int m = q*4 + j;
                float h = fmaxf(fmaf(a, wr[m], fmaf(xv, wo[m], br[m])), 0.f);
                hn[m] = (h - mu) * rs * gg[j] + bb_[j];
            }
        }
        float y1[CC1];
        #pragma unroll
        for (int o = 0; o < CC1; ++o) {
            float a1 = gb1[o];
            #pragma unroll
            for (int m = 0; m < MM; ++m) a1 = fmaf(gw1[o*MM+m], hn[m], a1);
            y1[o] = fmaxf(a1, 0.f) * sb1[o] + tb1[o];
        }
        #pragma unroll
        for (int p = 0; p < CC2; ++p) {
            float a2 = gb2[p];
            #pragma unroll
            for (int o = 0; o < CC1; ++o) a2 = fmaf(gw2[p*CC1+o], y1[o], a2);
            zb[p*NN + n] = fmaxf(a2, 0.f) * sb2[p] + tb2[p];
        }
    }
}

// ------------- FC1 GEMM: split-K partials (no atomics) -------------
#define GK_CHUNK 288   /* grid.z = 31; 31*288 = 8928 >= 8828 */
__global__ __launch_bounds__(256)
void k_fc1_part(const float* __restrict__ z, const float* __restrict__ W1,
                float* __restrict__ out1_part)
{
    __shared__ float zs[64*36];
    __shared__ float ws_[32*68];
    const int bt = blockIdx.x, jt = blockIdx.y, ks = blockIdx.z;
    const int t = threadIdx.x;
    const int tb = t >> 4, tj = t & 15;
    const int k0 = ks * GK_CHUNK;
    const int kend = min(k0 + GK_CHUNK, KK1);
    float acc[4][4] = {};
    const int zrow = t >> 2, zcol = (t & 3) * 8;
    const int wrow = t >> 3, wcol = (t & 7) * 8;

    for (int kc = k0; kc < kend; kc += 32) {
        const float* zsrc = z + (size_t)(bt*64 + zrow)*KK1 + kc + zcol;
        #pragma unroll
        for (int q = 0; q < 2; ++q) {
            int k = kc + zcol + q*4;
            float4 v;
            if (k + 3 < kend) v = *reinterpret_cast<const float4*>(zsrc + q*4);
            else {
                v.x = (k+0 < kend) ? zsrc[q*4+0] : 0.f;
                v.y = (k+1 < kend) ? zsrc[q*4+1] : 0.f;
                v.z = (k+2 < kend) ? zsrc[q*4+2] : 0.f;
                v.w = (k+3 < kend) ? zsrc[q*4+3] : 0.f;
            }
            *reinterpret_cast<float4*>(&zs[zrow*36 + zcol + q*4]) = v;
        }
        {
            int k = kc + wrow;
            const float* wsrc = W1 + (size_t)k*HH1 + jt*64 + wcol;
            #pragma unroll
            for (int q = 0; q < 2; ++q) {
                float4 v;
                if (k < kend) v = *reinterpret_cast<const float4*>(wsrc + q*4);
                else v = float4{0.f,0.f,0.f,0.f};
                *reinterpret_cast<float4*>(&ws_[wrow*68 + wcol + q*4]) = v;
            }
        }
        __syncthreads();
        #pragma unroll
        for (int kk = 0; kk < 32; ++kk) {
            float4 w4 = *reinterpret_cast<const float4*>(&ws_[kk*68 + tj*4]);
            float zv[4], wv[4] = {w4.x, w4.y, w4.z, w4.w};
            #pragma unroll
            for (int ib = 0; ib < 4; ++ib) zv[ib] = zs[(tb*4+ib)*36 + kk];
            #pragma unroll
            for (int ib = 0; ib < 4; ++ib)
                #pragma unroll
                for (int ij = 0; ij < 4; ++ij)
                    acc[ib][ij] = fmaf(zv[ib], wv[ij], acc[ib][ij]);
        }
        __syncthreads();
    }
    #pragma unroll
    for (int ib = 0; ib < 4; ++ib) {
        int row = bt*64 + tb*4 + ib;
        float4 v = make_float4(acc[ib][0], acc[ib][1], acc[ib][2], acc[ib][3]);
        *reinterpret_cast<float4*>(
            &out1_part[((size_t)ks*256 + row)*HH1 + jt*64 + tj*4]) = v;
    }
}

// ------------- tail: sum partials -> bn-relu -> FC2 -> bn-relu -> dot -------------
__global__ __launch_bounds__(256)
void k_tail_part(const float* __restrict__ out1_part,
            const float* __restrict__ fc_b1, const float* __restrict__ fbn1_g,
            const float* __restrict__ fbn1_b,
            const float* __restrict__ W2, const float* __restrict__ fc_b2,
            const float* __restrict__ fbn2_g, const float* __restrict__ fbn2_b,
            const float* __restrict__ fc1_w, const float* __restrict__ fc1_b,
            float* __restrict__ out)
{
    __shared__ float o1s[HH1];
    const int b = blockIdx.x, t = threadIdx.x;
    float raw = fc_b1[t];
    #pragma unroll 4
    for (int ks = 0; ks < 31; ++ks)
        raw += out1_part[((size_t)ks*256 + b)*HH1 + t];
    o1s[t] = fmaxf(raw * (BN_SCALE * fbn1_g[t]) + fbn1_b[t], 0.f);
    __syncthreads();
    if (t < HH2) {
        float acc = fc_b2[t];
        #pragma unroll 4
        for (int j = 0; j < HH1; ++j) acc = fmaf(o1s[j], W2[j*HH2 + t], acc);
        float v2 = fmaxf(acc * (BN_SCALE * fbn2_g[t]) + fbn2_b[t], 0.f);
        float c = v2 * fc1_w[t];
        #pragma unroll
        for (int off = 32; off; off >>= 1) c += __shfl_down(c, off);
        if (t == 0) out[b] = c + fc1_b[0];
    }
}

// =================== fallback path (round-1, proven; used if ws too small) ===================
__global__ __launch_bounds__(256)
void k_edge(const int* __restrict__ src, const int* __restrict__ dst,
            const float* __restrict__ ew, const float* __restrict__ x,
            float* __restrict__ agg)
{
    int i = blockIdx.x * 256 + threadIdx.x;
    const int4   s4 = reinterpret_cast<const int4*>(src)[i];
    const int4   d4 = reinterpret_cast<const int4*>(dst)[i];
    const float4 w4 = reinterpret_cast<const float4*>(ew)[i];
    unsafeAtomicAdd(&agg[d4.x], x[s4.x] * w4.x);
    unsafeAtomicAdd(&agg[d4.y], x[s4.y] * w4.y);
    unsafeAtomicAdd(&agg[d4.z], x[s4.z] * w4.z);
    unsafeAtomicAdd(&agg[d4.w], x[s4.w] * w4.w);
}

__global__ __launch_bounds__(256)
void k_sample(const float* __restrict__ x, const float* __restrict__ agg,
              const float* __restrict__ w_root, const float* __restrict__ w_rel,
              const float* __restrict__ b_rel,
              const float* __restrict__ ln_g, const float* __restrict__ ln_b,
              const float* __restrict__ gc1_w, const float* __restrict__ gc1_b,
              const float* __restrict__ bn1_g, const float* __restrict__ bn1_b,
              const float* __restrict__ gc2_w, const float* __restrict__ gc2_b,
              const float* __restrict__ bn2_g, const float* __restrict__ bn2_b,
              float* __restrict__ z)
{
    __shared__ float xs[NN], as[NN];
    __shared__ float gw1[CC1*MM], gb1[CC1], sb1[CC1], tb1[CC1];
    __shared__ float gw2[CC2*CC1], gb2[CC2], sb2[CC2], tb2[CC2];
    __shared__ float redS[4], redQ[4];
    __shared__ float s_mu, s_rs;

    const int b = blockIdx.x, t = threadIdx.x;
    const float* xb = x + b*NN;
    const float* ab = agg + b*NN;
    for (int n = t; n < NN; n += 256) { xs[n] = xb[n]; as[n] = ab[n]; }
    if (t < CC1*MM) gw1[t] = gc1_w[t];
    if (t >= 192 && t < 192+CC1) { int o = t-192; gb1[o]=gc1_b[o]; sb1[o]=BN_SCALE*bn1_g[o]; tb1[o]=bn1_b[o]; }
    if (t >= 208 && t < 208+CC2*CC1) gw2[t-208] = gc2_w[t-208];
    if (t >= 240 && t < 240+CC2) { int p=t-240; gb2[p]=gc2_b[p]; sb2[p]=BN_SCALE*bn2_g[p]; tb2[p]=bn2_b[p]; }

    float wr[MM], br[MM], wo[MM];
    #pragma unroll
    for (int m = 0; m < MM; ++m) { wr[m]=w_rel[m]; br[m]=b_rel[m]; wo[m]=w_root[m]; }
    __syncthreads();

    float S = 0.f, Q = 0.f;
    for (int n = t; n < NN; n += 256) {
        float a = as[n], xv = xs[n];
        #pragma unroll
        for (int m = 0; m < MM; ++m) {
            float h = fmaxf(fmaf(a, wr[m], fmaf(xv, wo[m], br[m])), 0.f);
            S += h; Q += h*h;
        }
    }
    #pragma unroll
    for (int off = 32; off; off >>= 1) { S += __shfl_down(S, off); Q += __shfl_down(Q, off); }
    if ((t & 63) == 0) { redS[t>>6] = S; redQ[t>>6] = Q; }
    __syncthreads();
    if (t == 0) {
        float SS = redS[0]+redS[1]+redS[2]+redS[3];
        float QQ = redQ[0]+redQ[1]+redQ[2]+redQ[3];
        const float inv = 1.f / (float)(NN*MM);
        float mu = SS * inv;
        float var = QQ * inv - mu*mu;
        s_mu = mu; s_rs = rsqrtf(var + LN_EPS);
    }
    __syncthreads();
    const float mu = s_mu, rs = s_rs;

    float* zb = z + (size_t)b * KK1;
    for (int n = t; n < NN; n += 256) {
        float a = as[n], xv = xs[n];
        float hn[MM];
        const float4* g4  = reinterpret_cast<const float4*>(ln_g + n*MM);
        const float4* be4 = reinterpret_cast<const float4*>(ln_b + n*MM);
        #pragma unroll
        for (int q = 0; q < 4; ++q) {
            float4 g = g4[q], be = be4[q];
            float gg[4]  = {g.x, g.y, g.z, g.w};
            float bb_[4] = {be.x, be.y, be.z, be.w};
            #pragma unroll
            for (int j = 0; j < 4; ++j) {
                int m = q*4 + j;
                float h = fmaxf(fmaf(a, wr[m], fmaf(xv, wo[m], br[m])), 0.f);
                hn[m] = (h - mu) * rs * gg[j] + bb_[j];
            }
        }
        float y1[CC1];
        #pragma unroll
        for (int o = 0; o < CC1; ++o) {
            float a1 = gb1[o];
            #pragma unroll
            for (int m = 0; m < MM; ++m) a1 = fmaf(gw1[o*MM+m], hn[m], a1);
            y1[o] = fmaxf(a1, 0.f) * sb1[o] + tb1[o];
        }
        #pragma unroll
        for (int p = 0; p < CC2; ++p) {
            float a2 = gb2[p];
            #pragma unroll
            for (int o = 0; o < CC1; ++o) a2 = fmaf(gw2[p*CC1+o], y1[o], a2);
            zb[p*NN + n] = fmaxf(a2, 0.f) * sb2[p] + tb2[p];
        }
    }
}

__global__ __launch_bounds__(256)
void k_fc1(const float* __restrict__ z, const float* __restrict__ W1,
           float* __restrict__ out1_raw)
{
    __shared__ float zs[64*36];
    __shared__ float ws_[32*68];
    const int bt = blockIdx.x, jt = blockIdx.y, ks = blockIdx.z;
    const int t = threadIdx.x;
    const int tb = t >> 4, tj = t & 15;
    const int k0 = ks * GK_CHUNK;
    const int kend = min(k0 + GK_CHUNK, KK1);
    float acc[4][4] = {};
    const int zrow = t >> 2, zcol = (t & 3) * 8;
    const int wrow = t >> 3, wcol = (t & 7) * 8;

    for (int kc = k0; kc < kend; kc += 32) {
        const float* zsrc = z + (size_t)(bt*64 + zrow)*KK1 + kc + zcol;
        #pragma unroll
        for (int q = 0; q < 2; ++q) {
            int k = kc + zcol + q*4;
            float4 v;
            if (k + 3 < kend) v = *reinterpret_cast<const float4*>(zsrc + q*4);
            else {
                v.x = (k+0 < kend) ? zsrc[q*4+0] : 0.f;
                v.y = (k+1 < kend) ? zsrc[q*4+1] : 0.f;
                v.z = (k+2 < kend) ? zsrc[q*4+2] : 0.f;
                v.w = (k+3 < kend) ? zsrc[q*4+3] : 0.f;
            }
            *reinterpret_cast<float4*>(&zs[zrow*36 + zcol + q*4]) = v;
        }
        {
            int k = kc + wrow;
            const float* wsrc = W1 + (size_t)k*HH1 + jt*64 + wcol;
            #pragma unroll
            for (int q = 0; q < 2; ++q) {
                float4 v;
                if (k < kend) v = *reinterpret_cast<const float4*>(wsrc + q*4);
                else v = float4{0.f,0.f,0.f,0.f};
                *reinterpret_cast<float4*>(&ws_[wrow*68 + wcol + q*4]) = v;
            }
        }
        __syncthreads();
        #pragma unroll
        for (int kk = 0; kk < 32; ++kk) {
            float4 w4 = *reinterpret_cast<const float4*>(&ws_[kk*68 + tj*4]);
            float zv[4], wv[4] = {w4.x, w4.y, w4.z, w4.w};
            #pragma unroll
            for (int ib = 0; ib < 4; ++ib) zv[ib] = zs[(tb*4+ib)*36 + kk];
            #pragma unroll
            for (int ib = 0; ib < 4; ++ib)
                #pragma unroll
                for (int ij = 0; ij < 4; ++ij)
                    acc[ib][ij] = fmaf(zv[ib], wv[ij], acc[ib][ij]);
        }
        __syncthreads();
    }
    #pragma unroll
    for (int ib = 0; ib < 4; ++ib) {
        int row = bt*64 + tb*4 + ib;
        #pragma unroll
        for (int ij = 0; ij < 4; ++ij)
            unsafeAtomicAdd(&out1_raw[row*HH1 + jt*64 + tj*4 + ij], acc[ib][ij]);
    }
}

__global__ __launch_bounds__(256)
void k_tail(const float* __restrict__ out1_raw,
            const float* __restrict__ fc_b1, const float* __restrict__ fbn1_g,
            const float* __restrict__ fbn1_b,
            const float* __restrict__ W2, const float* __restrict__ fc_b2,
            const float* __restrict__ fbn2_g, const float* __restrict__ fbn2_b,
            const float* __restrict__ fc1_w, const float* __restrict__ fc1_b,
            float* __restrict__ out)
{
    __shared__ float o1s[HH1];
    const int b = blockIdx.x, t = threadIdx.x;
    float raw = out1_raw[b*HH1 + t] + fc_b1[t];
    o1s[t] = fmaxf(raw * (BN_SCALE * fbn1_g[t]) + fbn1_b[t], 0.f);
    __syncthreads();
    if (t < HH2) {
        float acc = fc_b2[t];
        #pragma unroll 4
        for (int j = 0; j < HH1; ++j) acc = fmaf(o1s[j], W2[j*HH2 + t], acc);
        float v2 = fmaxf(acc * (BN_SCALE * fbn2_g[t]) + fbn2_b[t], 0.f);
        float c = v2 * fc1_w[t];
        #pragma unroll
        for (int off = 32; off; off >>= 1) c += __shfl_down(c, off);
        if (t == 0) out[b] = c + fc1_b[0];
    }
}

extern "C" void kernel_launch(void* const* d_in, const int* in_sizes, int n_in,
                              void* d_out, int out_size, void* d_ws, size_t ws_size,
                              hipStream_t stream)
{
    const float* x      = (const float*)d_in[0];
    const int*   ei     = (const int*)  d_in[1];
    const float* ew     = (const float*)d_in[2];
    const float* w_root = (const float*)d_in[3];
    const float* w_rel  = (const float*)d_in[4];
    const float* b_rel  = (const float*)d_in[5];
    const float* ln_g   = (const float*)d_in[6];
    const float* ln_b   = (const float*)d_in[7];
    const float* gc1_w  = (const float*)d_in[8];
    const float* gc1_b  = (const float*)d_in[9];
    const float* bn1_g  = (const float*)d_in[10];
    const float* bn1_b  = (const float*)d_in[11];
    const float* gc2_w  = (const float*)d_in[12];
    const float* gc2_b  = (const float*)d_in[13];
    const float* bn2_g  = (const float*)d_in[14];
    const float* bn2_b  = (const float*)d_in[15];
    const float* fc_w1  = (const float*)d_in[16];
    const float* fc_b1  = (const float*)d_in[17];
    const float* fbn1_g = (const float*)d_in[18];
    const float* fbn1_b = (const float*)d_in[19];
    const float* fc_w2  = (const float*)d_in[20];
    const float* fc_b2  = (const float*)d_in[21];
    const float* fbn2_g = (const float*)d_in[22];
    const float* fbn2_b = (const float*)d_in[23];
    const float* fc1_w  = (const float*)d_in[24];
    const float* fc1_b  = (const float*)d_in[25];
    float* out = (float*)d_out;

    char* ws = (char*)d_ws;
    // layout: recs | stab | paggr (reused as o1p) | zbuf   = 181.5 MB (proven)
    const size_t off_recs  = 0;                                   // 134,217,728
    const size_t off_stab  = off_recs + (size_t)NBLK*EPB*8;       // +2,097,152
    const size_t off_paggr = off_stab + (size_t)NBLK*NBK*2;
    const size_t sz_paggr  = (size_t)RSP6*NGRP*GRP*NN*4;          // 36,175,872 (>= o1p 8,126,464)
    const size_t off_zbuf  = off_paggr + sz_paggr;
    const size_t need      = off_zbuf + (size_t)BB*KK1*4;         // 181,530,624

    if (ws_size >= need) {
        uint2*          recs  = (uint2*)(ws + off_recs);
        unsigned short* stab  = (unsigned short*)(ws + off_stab);
        float*          paggr = (float*)(ws + off_paggr);
        float*          zbuf  = (float*)(ws + off_zbuf);
        float*          o1p   = (float*)(ws + off_paggr);  // reused after k_ln_conv

        k_place4<<<NBLK, TPB, 0, stream>>>(ei, ei + EE, ew, recs, stab);
        k_replay6<<<NGRP*RSP6, 512, 0, stream>>>(recs, stab, x, paggr);
        k_ln_conv<<<BB, 512, 0, stream>>>(x, paggr,
                                         w_root, w_rel, b_rel, ln_g, ln_b,
                                         gc1_w, gc1_b, bn1_g, bn1_b,
                                         gc2_w, gc2_b, bn2_g, bn2_b, zbuf);
        k_fc1_part<<<dim3(4,4,31), 256, 0, stream>>>(zbuf, fc_w1, o1p);
        k_tail_part<<<BB, 256, 0, stream>>>(o1p, fc_b1, fbn1_g, fbn1_b,
                                       fc_w2, fc_b2, fbn2_g, fbn2_b,
                                       fc1_w, fc1_b, out);
    } else {
        // round-1 fallback (proven <= 11.6 MB ws)
        float* agg      = (float*)(ws);
        float* zbuf     = (float*)(ws + 2259968);
        float* out1_raw = (float*)(ws + 2259968 + 9039872);

        hipMemsetAsync(agg,      0, (size_t)BB*NN*sizeof(float),  stream);
        hipMemsetAsync(out1_raw, 0, (size_t)BB*HH1*sizeof(float), stream);

        k_edge<<<EE/4/256, 256, 0, stream>>>(ei, ei + EE, ew, x, agg);
        k_sample<<<BB, 256, 0, stream>>>(x, agg, w_root, w_rel, b_rel, ln_g, ln_b,
                                         gc1_w, gc1_b, bn1_g, bn1_b,
                                         gc2_w, gc2_b, bn2_g, bn2_b, zbuf);
        k_fc1<<<dim3(4,4,31), 256, 0, stream>>>(zbuf, fc_w1, out1_raw);
        k_tail<<<BB, 256, 0, stream>>>(out1_raw, fc_b1, fbn1_g, fbn1_b,
                                       fc_w2, fc_b2, fbn2_g, fbn2_b,
                                       fc1_w, fc1_b, out);
    }
}

// Round 15
// 305.245 us; speedup vs baseline: 1.1413x; 1.0134x over previous
//
#include <hip/hip_runtime.h>
#include <hip/hip_bf16.h>

#define BB   256
#define NN   2207
#define MM   16
#define EE   16777216
#define CC1  12
#define CC2  4
#define HH1  256
#define HH2  64
#define KK1  (CC2*NN)          /* 8828 */
#define LN_EPS 1e-5f
#define BN_SCALE 0.9999950000374997f   /* 1/sqrt(1+1e-5) */
#define NBK  256               /* buckets == samples */
#define MAGIC 1946067ull       /* ceil(2^32/2207), exact for d < 564992 */
#define EPB  4096              /* edges per bin block */
#define TPB  512
#define EPT  (EPB/TPB)         /* 8 edges per thread */
#define NBLK (EE/EPB)          /* 4096 bin blocks */
#define GRP  4                 /* samples per replay group */
#define NGRP (NBK/GRP)         /* 64 groups */
#define RSP6 16                /* replay splits; regions/block = 256 */

static __device__ __forceinline__ unsigned bucket_of(int d) {
    return (unsigned)(((unsigned long long)(unsigned)d * MAGIC) >> 32);
}

// ===== PASS 1: rank + scan + direct scatter to block-private regions (round-10 proven) =====
// record = ( src<<12 | dst_local , w )  -- gather deferred to replay
__global__ __launch_bounds__(TPB, 8)
void k_place4(const int* __restrict__ src, const int* __restrict__ dst,
              const float* __restrict__ ew,
              uint2* __restrict__ recs, unsigned short* __restrict__ stab)
{
    __shared__ unsigned int hist[NBK], start[NBK];
    __shared__ unsigned int wtot[4];

    const int t = threadIdx.x;
    if (t < NBK) hist[t] = 0;
    __syncthreads();

    const int i4base = blockIdx.x * (EPB/4);
    unsigned key[EPT];
    float    wv[EPT];
    unsigned short rk[EPT];
    unsigned char  bk[EPT];
    #pragma unroll
    for (int q = 0; q < EPT/4; ++q) {
        int i4 = i4base + q*TPB + t;
        int4   s4 = reinterpret_cast<const int4*>(src)[i4];
        int4   d4 = reinterpret_cast<const int4*>(dst)[i4];
        float4 w4 = reinterpret_cast<const float4*>(ew)[i4];
        unsigned b0 = bucket_of(d4.x), b1 = bucket_of(d4.y);
        unsigned b2 = bucket_of(d4.z), b3 = bucket_of(d4.w);
        unsigned r0 = atomicAdd(&hist[b0], 1u);
        unsigned r1 = atomicAdd(&hist[b1], 1u);
        unsigned r2 = atomicAdd(&hist[b2], 1u);
        unsigned r3 = atomicAdd(&hist[b3], 1u);
        key[q*4+0] = ((unsigned)s4.x << 12) | (unsigned)(d4.x - (int)(b0*NN));
        key[q*4+1] = ((unsigned)s4.y << 12) | (unsigned)(d4.y - (int)(b1*NN));
        key[q*4+2] = ((unsigned)s4.z << 12) | (unsigned)(d4.z - (int)(b2*NN));
        key[q*4+3] = ((unsigned)s4.w << 12) | (unsigned)(d4.w - (int)(b3*NN));
        wv[q*4+0] = w4.x; wv[q*4+1] = w4.y; wv[q*4+2] = w4.z; wv[q*4+3] = w4.w;
        rk[q*4+0] = (unsigned short)r0; rk[q*4+1] = (unsigned short)r1;
        rk[q*4+2] = (unsigned short)r2; rk[q*4+3] = (unsigned short)r3;
        bk[q*4+0] = (unsigned char)b0; bk[q*4+1] = (unsigned char)b1;
        bk[q*4+2] = (unsigned char)b2; bk[q*4+3] = (unsigned char)b3;
    }
    __syncthreads();

    // exclusive prefix scan of hist[256] (4 waves of 64)
    if (t < NBK) {
        unsigned h = hist[t], v = h;
        #pragma unroll
        for (int off = 1; off < 64; off <<= 1) {
            unsigned u = __shfl_up(v, off);
            if ((t & 63) >= off) v += u;
        }
        start[t] = v - h;
        if ((t & 63) == 63) wtot[t >> 6] = v;
    }
    __syncthreads();
    if (t < NBK) {
        const int w = t >> 6;
        unsigned wo = 0;
        if (w > 0) wo += wtot[0];
        if (w > 1) wo += wtot[1];
        if (w > 2) wo += wtot[2];
        start[t] += wo;
        stab[blockIdx.x * NBK + t] = (unsigned short)(start[t]);
    }
    __syncthreads();

    uint2* rb = recs + (size_t)blockIdx.x * EPB;
    #pragma unroll
    for (int e = 0; e < EPT; ++e)
        rb[start[bk[e]] + (unsigned)rk[e]] =
            make_uint2(key[e], __float_as_uint(wv[e]));
}

// ===== PASS 2a: sample-GROUP replay, 2-deep software pipeline =====
// stage i+2: bounds load; stage i+1: record loads (2/lane regs); stage i: process
__global__ __launch_bounds__(512, 8)
void k_replay8(const uint2* __restrict__ recs, const unsigned short* __restrict__ stab,
               const float* __restrict__ x, float* __restrict__ paggr)
{
    __shared__ float acc[GRP*NN];               // 35,312 B
    const int t = threadIdx.x;
    const int g = blockIdx.x & (NGRP - 1);      // sample group (64)
    const int r = blockIdx.x >> 6;              // split 0..RSP6-1
    for (int n = t; n < GRP*NN; n += 512) acc[n] = 0.f;
    __syncthreads();

    const int lane = t & 63, w = t >> 6;        // 8 waves
    const int nreg = NBLK / RSP6;               // 256 regions per block
    const int j0 = g * GRP;
    const bool last = (j0 + GRP >= NBK);

    const int region0 = r * nreg + w;

    unsigned cb0,cb1,cb2,cb3,cb4;               // current bounds (ready)
    unsigned nb0,nb1,nb2,nb3,nb4;               // next bounds (ready)
    uint2 cra, crb;                             // current records (ready)
    const uint2* crp;

    // prologue: bounds for region0, region0+8; records for region0
    {
        const unsigned short* sb = stab + (size_t)region0 * NBK + j0;
        cb0=sb[0]; cb1=sb[1]; cb2=sb[2]; cb3=sb[3];
        cb4 = last ? (unsigned)EPB : (unsigned)sb[4];
    }
    {
        const unsigned short* sb = stab + (size_t)(region0+8) * NBK + j0;
        nb0=sb[0]; nb1=sb[1]; nb2=sb[2]; nb3=sb[3];
        nb4 = last ? (unsigned)EPB : (unsigned)sb[4];
    }
    crp = recs + (size_t)region0 * EPB;
    {
        unsigned u0 = cb0 + (unsigned)lane;
        cra = (u0 < cb4) ? crp[u0] : make_uint2(0u,0u);
        unsigned u1 = u0 + 64u;
        crb = (u1 < cb4) ? crp[u1] : make_uint2(0u,0u);
    }
    int regionN = region0 + 8;

    for (int ri = w; ri < nreg; ri += 8) {
        // stage 1: issue record loads for NEXT region (bounds nb ready)
        uint2 nra = make_uint2(0u,0u), nrb = make_uint2(0u,0u);
        const uint2* nrp = recs + (size_t)regionN * EPB;
        if (ri + 8 < nreg) {
            unsigned u0 = nb0 + (unsigned)lane;
            if (u0 < nb4) nra = nrp[u0];
            unsigned u1 = u0 + 64u;
            if (u1 < nb4) nrb = nrp[u1];
        }
        // stage 2: issue bounds load for region+16
        unsigned tb0=0,tb1=0,tb2=0,tb3=0,tb4=0;
        if (ri + 16 < nreg) {
            const unsigned short* sb = stab + (size_t)(regionN + 8) * NBK + j0;
            tb0=sb[0]; tb1=sb[1]; tb2=sb[2]; tb3=sb[3];
            tb4 = last ? (unsigned)EPB : (unsigned)sb[4];
        }
        // stage 3: process CURRENT region (records in registers)
        {
            unsigned u0 = cb0 + (unsigned)lane;
            if (u0 < cb4) {
                unsigned so = (u0>=cb1)+(u0>=cb2)+(u0>=cb3);
                unsafeAtomicAdd(&acc[so*NN + (cra.x & 0xFFFu)],
                                x[cra.x >> 12] * __uint_as_float(cra.y));
            }
            unsigned u1 = u0 + 64u;
            if (u1 < cb4) {
                unsigned so = (u1>=cb1)+(u1>=cb2)+(u1>=cb3);
                unsafeAtomicAdd(&acc[so*NN + (crb.x & 0xFFFu)],
                                x[crb.x >> 12] * __uint_as_float(crb.y));
            }
            for (unsigned u = u0 + 128u; u < cb4; u += 64u) {   // rare long-run tail
                uint2 rc = crp[u];
                unsigned so = (u>=cb1)+(u>=cb2)+(u>=cb3);
                unsafeAtomicAdd(&acc[so*NN + (rc.x & 0xFFFu)],
                                x[rc.x >> 12] * __uint_as_float(rc.y));
            }
        }
        // rotate pipeline
        cb0=nb0; cb1=nb1; cb2=nb2; cb3=nb3; cb4=nb4;
        cra=nra; crb=nrb; crp=nrp;
        nb0=tb0; nb1=tb1; nb2=tb2; nb3=tb3; nb4=tb4;
        regionN += 8;
    }
    __syncthreads();
    float* pa = paggr + (((size_t)r * NGRP + g) * GRP) * NN;
    for (int n = t; n < GRP*NN; n += 512) pa[n] = acc[n];
}

// ===== PASS 2b: sum partials + relu/LN/conv1/bn/conv2/bn -> z =====
__global__ __launch_bounds__(512)
void k_ln_conv(const float* __restrict__ x, const float* __restrict__ paggr,
              const float* __restrict__ w_root, const float* __restrict__ w_rel,
              const float* __restrict__ b_rel,
              const float* __restrict__ ln_g, const float* __restrict__ ln_b,
              const float* __restrict__ gc1_w, const float* __restrict__ gc1_b,
              const float* __restrict__ bn1_g, const float* __restrict__ bn1_b,
              const float* __restrict__ gc2_w, const float* __restrict__ gc2_b,
              const float* __restrict__ bn2_g, const float* __restrict__ bn2_b,
              float* __restrict__ z)
{
    __shared__ float xs[NN], acc[NN];
    __shared__ float gw1[CC1*MM], gb1[CC1], sb1[CC1], tb1[CC1];
    __shared__ float gw2[CC2*CC1], gb2[CC2], sb2[CC2], tb2[CC2];
    __shared__ float redS[8], redQ[8];
    __shared__ float s_mu, s_rs;

    const int b = blockIdx.x, t = threadIdx.x;
    const float* xb = x + b*NN;
    const float* pb = paggr + (((size_t)(b >> 2)) * GRP + (b & 3)) * NN;
    const size_t rstride = (size_t)NGRP * GRP * NN;
    for (int n = t; n < NN; n += 512) {
        xs[n] = xb[n];
        float a = 0.f;
        #pragma unroll
        for (int r = 0; r < RSP6; ++r)
            a += pb[(size_t)r * rstride + n];
        acc[n] = a;
    }
    if (t < CC1*MM) gw1[t] = gc1_w[t];
    if (t >= 192 && t < 192+CC1) { int o = t-192; gb1[o]=gc1_b[o]; sb1[o]=BN_SCALE*bn1_g[o]; tb1[o]=bn1_b[o]; }
    if (t >= 208 && t < 208+CC2*CC1) gw2[t-208] = gc2_w[t-208];
    if (t >= 240 && t < 240+CC2) { int p=t-240; gb2[p]=gc2_b[p]; sb2[p]=BN_SCALE*bn2_g[p]; tb2[p]=bn2_b[p]; }

    float wr[MM], br[MM], wo[MM];
    #pragma unroll
    for (int m = 0; m < MM; ++m) { wr[m]=w_rel[m]; br[m]=b_rel[m]; wo[m]=w_root[m]; }
    __syncthreads();

    float S = 0.f, Q = 0.f;
    for (int n = t; n < NN; n += 512) {
        float a = acc[n], xv = xs[n];
        #pragma unroll
        for (int m = 0; m < MM; ++m) {
            float h = fmaxf(fmaf(a, wr[m], fmaf(xv, wo[m], br[m])), 0.f);
            S += h; Q += h*h;
        }
    }
    #pragma unroll
    for (int off = 32; off; off >>= 1) { S += __shfl_down(S, off); Q += __shfl_down(Q, off); }
    if ((t & 63) == 0) { redS[t>>6] = S; redQ[t>>6] = Q; }
    __syncthreads();
    if (t == 0) {
        float SS = 0.f, QQ = 0.f;
        #pragma unroll
        for (int i = 0; i < 8; ++i) { SS += redS[i]; QQ += redQ[i]; }
        const float inv = 1.f / (float)(NN*MM);
        float mu = SS * inv;
        float var = QQ * inv - mu*mu;
        s_mu = mu; s_rs = rsqrtf(var + LN_EPS);
    }
    __syncthreads();
    const float mu = s_mu, rs = s_rs;

    float* zb = z + (size_t)b * KK1;
    for (int n = t; n < NN; n += 512) {
        float a = acc[n], xv = xs[n];
        float hn[MM];
        const float4* g4  = reinterpret_cast<const float4*>(ln_g + n*MM);
        const float4* be4 = reinterpret_cast<const float4*>(ln_b + n*MM);
        #pragma unroll
        for (int q = 0; q < 4; ++q) {
            float4 g = g4[q], be = be4[q];
            float gg[4]  = {g.x, g.y, g.z, g.w};
            float bb_[4] = {be.x, be.y, be.z, be.w};
            #pragma unroll
            for (int j = 0; j < 4; ++j) {
                int m = q*4 + j;
                float h = fmaxf(fmaf(a, wr[m], fmaf(xv, wo[m], br[m])), 0.f);
                hn[m] = (h - mu) * rs * gg[j] + bb_[j];
            }
        }
        float y1[CC1];
        #pragma unroll
        for (int o = 0; o < CC1; ++o) {
            float a1 = gb1[o];
            #pragma unroll
            for (int m = 0; m < MM; ++m) a1 = fmaf(gw1[o*MM+m], hn[m], a1);
            y1[o] = fmaxf(a1, 0.f) * sb1[o] + tb1[o];
        }
        #pragma unroll
        for (int p = 0; p < CC2; ++p) {
            float a2 = gb2[p];
            #pragma unroll
            for (int o = 0; o < CC1; ++o) a2 = fmaf(gw2[p*CC1+o], y1[o], a2);
            zb[p*NN + n] = fmaxf(a2, 0.f) * sb2[p] + tb2[p];
        }
    }
}

// ------------- FC1 GEMM: split-K partials (no atomics) -------------
#define GK_CHUNK 288   /* grid.z = 31; 31*288 = 8928 >= 8828 */
__global__ __launch_bounds__(256)
void k_fc1_part(const float* __restrict__ z, const float* __restrict__ W1,
                float* __restrict__ out1_part)
{
    __shared__ float zs[64*36];
    __shared__ float ws_[32*68];
    const int bt = blockIdx.x, jt = blockIdx.y, ks = blockIdx.z;
    const int t = threadIdx.x;
    const int tb = t >> 4, tj = t & 15;
    const int k0 = ks * GK_CHUNK;
    const int kend = min(k0 + GK_CHUNK, KK1);
    float acc[4][4] = {};
    const int zrow = t >> 2, zcol = (t & 3) * 8;
    const int wrow = t >> 3, wcol = (t & 7) * 8;

    for (int kc = k0; kc < kend; kc += 32) {
        const float* zsrc = z + (size_t)(bt*64 + zrow)*KK1 + kc + zcol;
        #pragma unroll
        for (int q = 0; q < 2; ++q) {
            int k = kc + zcol + q*4;
            float4 v;
            if (k + 3 < kend) v = *reinterpret_cast<const float4*>(zsrc + q*4);
            else {
                v.x = (k+0 < kend) ? zsrc[q*4+0] : 0.f;
                v.y = (k+1 < kend) ? zsrc[q*4+1] : 0.f;
                v.z = (k+2 < kend) ? zsrc[q*4+2] : 0.f;
                v.w = (k+3 < kend) ? zsrc[q*4+3] : 0.f;
            }
            *reinterpret_cast<float4*>(&zs[zrow*36 + zcol + q*4]) = v;
        }
        {
            int k = kc + wrow;
            const float* wsrc = W1 + (size_t)k*HH1 + jt*64 + wcol;
            #pragma unroll
            for (int q = 0; q < 2; ++q) {
                float4 v;
                if (k < kend) v = *reinterpret_cast<const float4*>(wsrc + q*4);
                else v = float4{0.f,0.f,0.f,0.f};
                *reinterpret_cast<float4*>(&ws_[wrow*68 + wcol + q*4]) = v;
            }
        }
        __syncthreads();
        #pragma unroll
        for (int kk = 0; kk < 32; ++kk) {
            float4 w4 = *reinterpret_cast<const float4*>(&ws_[kk*68 + tj*4]);
            float zv[4], wv[4] = {w4.x, w4.y, w4.z, w4.w};
            #pragma unroll
            for (int ib = 0; ib < 4; ++ib) zv[ib] = zs[(tb*4+ib)*36 + kk];
            #pragma unroll
            for (int ib = 0; ib < 4; ++ib)
                #pragma unroll
                for (int ij = 0; ij < 4; ++ij)
                    acc[ib][ij] = fmaf(zv[ib], wv[ij], acc[ib][ij]);
        }
        __syncthreads();
    }
    #pragma unroll
    for (int ib = 0; ib < 4; ++ib) {
        int row = bt*64 + tb*4 + ib;
        float4 v = make_float4(acc[ib][0], acc[ib][1], acc[ib][2], acc[ib][3]);
        *reinterpret_cast<float4*>(
            &out1_part[((size_t)ks*256 + row)*HH1 + jt*64 + tj*4]) = v;
    }
}

// ------------- tail: sum partials -> bn-relu -> FC2 -> bn-relu -> dot -------------
__global__ __launch_bounds__(256)
void k_tail_part(const float* __restrict__ out1_part,
            const float* __restrict__ fc_b1, const float* __restrict__ fbn1_g,
            const float* __restrict__ fbn1_b,
            const float* __restrict__ W2, const float* __restrict__ fc_b2,
            const float* __restrict__ fbn2_g, const float* __restrict__ fbn2_b,
            const float* __restrict__ fc1_w, const float* __restrict__ fc1_b,
            float* __restrict__ out)
{
    __shared__ float o1s[HH1];
    const int b = blockIdx.x, t = threadIdx.x;
    float raw = fc_b1[t];
    #pragma unroll 4
    for (int ks = 0; ks < 31; ++ks)
        raw += out1_part[((size_t)ks*256 + b)*HH1 + t];
    o1s[t] = fmaxf(raw * (BN_SCALE * fbn1_g[t]) + fbn1_b[t], 0.f);
    __syncthreads();
    if (t < HH2) {
        float acc = fc_b2[t];
        #pragma unroll 4
        for (int j = 0; j < HH1; ++j) acc = fmaf(o1s[j], W2[j*HH2 + t], acc);
        float v2 = fmaxf(acc * (BN_SCALE * fbn2_g[t]) + fbn2_b[t], 0.f);
        float c = v2 * fc1_w[t];
        #pragma unroll
        for (int off = 32; off; off >>= 1) c += __shfl_down(c, off);
        if (t == 0) out[b] = c + fc1_b[0];
    }
}

// =================== fallback path (round-1, proven; used if ws too small) ===================
__global__ __launch_bounds__(256)
void k_edge(const int* __restrict__ src, const int* __restrict__ dst,
            const float* __restrict__ ew, const float* __restrict__ x,
            float* __restrict__ agg)
{
    int i = blockIdx.x * 256 + threadIdx.x;
    const int4   s4 = reinterpret_cast<const int4*>(src)[i];
    const int4   d4 = reinterpret_cast<const int4*>(dst)[i];
    const float4 w4 = reinterpret_cast<const float4*>(ew)[i];
    unsafeAtomicAdd(&agg[d4.x], x[s4.x] * w4.x);
    unsafeAtomicAdd(&agg[d4.y], x[s4.y] * w4.y);
    unsafeAtomicAdd(&agg[d4.z], x[s4.z] * w4.z);
    unsafeAtomicAdd(&agg[d4.w], x[s4.w] * w4.w);
}

__global__ __launch_bounds__(256)
void k_sample(const float* __restrict__ x, const float* __restrict__ agg,
              const float* __restrict__ w_root, const float* __restrict__ w_rel,
              const float* __restrict__ b_rel,
              const float* __restrict__ ln_g, const float* __restrict__ ln_b,
              const float* __restrict__ gc1_w, const float* __restrict__ gc1_b,
              const float* __restrict__ bn1_g, const float* __restrict__ bn1_b,
              const float* __restrict__ gc2_w, const float* __restrict__ gc2_b,
              const float* __restrict__ bn2_g, const float* __restrict__ bn2_b,
              float* __restrict__ z)
{
    __shared__ float xs[NN], as[NN];
    __shared__ float gw1[CC1*MM], gb1[CC1], sb1[CC1], tb1[CC1];
    __shared__ float gw2[CC2*CC1], gb2[CC2], sb2[CC2], tb2[CC2];
    __shared__ float redS[4], redQ[4];
    __shared__ float s_mu, s_rs;

    const int b = blockIdx.x, t = threadIdx.x;
    const float* xb = x + b*NN;
    const float* ab = agg + b*NN;
    for (int n = t; n < NN; n += 256) { xs[n] = xb[n]; as[n] = ab[n]; }
    if (t < CC1*MM) gw1[t] = gc1_w[t];
    if (t >= 192 && t < 192+CC1) { int o = t-192; gb1[o]=gc1_b[o]; sb1[o]=BN_SCALE*bn1_g[o]; tb1[o]=bn1_b[o]; }
    if (t >= 208 && t < 208+CC2*CC1) gw2[t-208] = gc2_w[t-208];
    if (t >= 240 && t < 240+CC2) { int p=t-240; gb2[p]=gc2_b[p]; sb2[p]=BN_SCALE*bn2_g[p]; tb2[p]=bn2_b[p]; }

    float wr[MM], br[MM], wo[MM];
    #pragma unroll
    for (int m = 0; m < MM; ++m) { wr[m]=w_rel[m]; br[m]=b_rel[m]; wo[m]=w_root[m]; }
    __syncthreads();

    float S = 0.f, Q = 0.f;
    for (int n = t; n < NN; n += 256) {
        float a = as[n], xv = xs[n];
        #pragma unroll
        for (int m = 0; m < MM; ++m) {
            float h = fmaxf(fmaf(a, wr[m], fmaf(xv, wo[m], br[m])), 0.f);
            S += h; Q += h*h;
        }
    }
    #pragma unroll
    for (int off = 32; off; off >>= 1) { S += __shfl_down(S, off); Q += __shfl_down(Q, off); }
    if ((t & 63) == 0) { redS[t>>6] = S; redQ[t>>6] = Q; }
    __syncthreads();
    if (t == 0) {
        float SS = redS[0]+redS[1]+redS[2]+redS[3];
        float QQ = redQ[0]+redQ[1]+redQ[2]+redQ[3];
        const float inv = 1.f / (float)(NN*MM);
        float mu = SS * inv;
        float var = QQ * inv - mu*mu;
        s_mu = mu; s_rs = rsqrtf(var + LN_EPS);
    }
    __syncthreads();
    const float mu = s_mu, rs = s_rs;

    float* zb = z + (size_t)b * KK1;
    for (int n = t; n < NN; n += 256) {
        float a = as[n], xv = xs[n];
        float hn[MM];
        const float4* g4  = reinterpret_cast<const float4*>(ln_g + n*MM);
        const float4* be4 = reinterpret_cast<const float4*>(ln_b + n*MM);
        #pragma unroll
        for (int q = 0; q < 4; ++q) {
            float4 g = g4[q], be = be4[q];
            float gg[4]  = {g.x, g.y, g.z, g.w};
            float bb_[4] = {be.x, be.y, be.z, be.w};
            #pragma unroll
            for (int j = 0; j < 4; ++j) {
                int m = q*4 + j;
                float h = fmaxf(fmaf(a, wr[m], fmaf(xv, wo[m], br[m])), 0.f);
                hn[m] = (h - mu) * rs * gg[j] + bb_[j];
            }
        }
        float y1[CC1];
        #pragma unroll
        for (int o = 0; o < CC1; ++o) {
            float a1 = gb1[o];
            #pragma unroll
            for (int m = 0; m < MM; ++m) a1 = fmaf(gw1[o*MM+m], hn[m], a1);
            y1[o] = fmaxf(a1, 0.f) * sb1[o] + tb1[o];
        }
        #pragma unroll
        for (int p = 0; p < CC2; ++p) {
            float a2 = gb2[p];
            #pragma unroll
            for (int o = 0; o < CC1; ++o) a2 = fmaf(gw2[p*CC1+o], y1[o], a2);
            zb[p*NN + n] = fmaxf(a2, 0.f) * sb2[p] + tb2[p];
        }
    }
}

__global__ __launch_bounds__(256)
void k_fc1(const float* __restrict__ z, const float* __restrict__ W1,
           float* __restrict__ out1_raw)
{
    __shared__ float zs[64*36];
    __shared__ float ws_[32*68];
    const int bt = blockIdx.x, jt = blockIdx.y, ks = blockIdx.z;
    const int t = threadIdx.x;
    const int tb = t >> 4, tj = t & 15;
    const int k0 = ks * GK_CHUNK;
    const int kend = min(k0 + GK_CHUNK, KK1);
    float acc[4][4] = {};
    const int zrow = t >> 2, zcol = (t & 3) * 8;
    const int wrow = t >> 3, wcol = (t & 7) * 8;

    for (int kc = k0; kc < kend; kc += 32) {
        const float* zsrc = z + (size_t)(bt*64 + zrow)*KK1 + kc + zcol;
        #pragma unroll
        for (int q = 0; q < 2; ++q) {
            int k = kc + zcol + q*4;
            float4 v;
            if (k + 3 < kend) v = *reinterpret_cast<const float4*>(zsrc + q*4);
            else {
                v.x = (k+0 < kend) ? zsrc[q*4+0] : 0.f;
                v.y = (k+1 < kend) ? zsrc[q*4+1] : 0.f;
                v.z = (k+2 < kend) ? zsrc[q*4+2] : 0.f;
                v.w = (k+3 < kend) ? zsrc[q*4+3] : 0.f;
            }
            *reinterpret_cast<float4*>(&zs[zrow*36 + zcol + q*4]) = v;
        }
        {
            int k = kc + wrow;
            const float* wsrc = W1 + (size_t)k*HH1 + jt*64 + wcol;
            #pragma unroll
            for (int q = 0; q < 2; ++q) {
                float4 v;
                if (k < kend) v = *reinterpret_cast<const float4*>(wsrc + q*4);
                else v = float4{0.f,0.f,0.f,0.f};
                *reinterpret_cast<float4*>(&ws_[wrow*68 + wcol + q*4]) = v;
            }
        }
        __syncthreads();
        #pragma unroll
        for (int kk = 0; kk < 32; ++kk) {
            float4 w4 = *reinterpret_cast<const float4*>(&ws_[kk*68 + tj*4]);
            float zv[4], wv[4] = {w4.x, w4.y, w4.z, w4.w};
            #pragma unroll
            for (int ib = 0; ib < 4; ++ib) zv[ib] = zs[(tb*4+ib)*36 + kk];
            #pragma unroll
            for (int ib = 0; ib < 4; ++ib)
                #pragma unroll
                for (int ij = 0; ij < 4; ++ij)
                    acc[ib][ij] = fmaf(zv[ib], wv[ij], acc[ib][ij]);
        }
        __syncthreads();
    }
    #pragma unroll
    for (int ib = 0; ib < 4; ++ib) {
        int row = bt*64 + tb*4 + ib;
        #pragma unroll
        for (int ij = 0; ij < 4; ++ij)
            unsafeAtomicAdd(&out1_raw[row*HH1 + jt*64 + tj*4 + ij], acc[ib][ij]);
    }
}

__global__ __launch_bounds__(256)
void k_tail(const float* __restrict__ out1_raw,
            const float* __restrict__ fc_b1, const float* __restrict__ fbn1_g,
            const float* __restrict__ fbn1_b,
            const float* __restrict__ W2, const float* __restrict__ fc_b2,
            const float* __restrict__ fbn2_g, const float* __restrict__ fbn2_b,
            const float* __restrict__ fc1_w, const float* __restrict__ fc1_b,
            float* __restrict__ out)
{
    __shared__ float o1s[HH1];
    const int b = blockIdx.x, t = threadIdx.x;
    float raw = out1_raw[b*HH1 + t] + fc_b1[t];
    o1s[t] = fmaxf(raw * (BN_SCALE * fbn1_g[t]) + fbn1_b[t], 0.f);
    __syncthreads();
    if (t < HH2) {
        float acc = fc_b2[t];
        #pragma unroll 4
        for (int j = 0; j < HH1; ++j) acc = fmaf(o1s[j], W2[j*HH2 + t], acc);
        float v2 = fmaxf(acc * (BN_SCALE * fbn2_g[t]) + fbn2_b[t], 0.f);
        float c = v2 * fc1_w[t];
        #pragma unroll
        for (int off = 32; off; off >>= 1) c += __shfl_down(c, off);
        if (t == 0) out[b] = c + fc1_b[0];
    }
}

extern "C" void kernel_launch(void* const* d_in, const int* in_sizes, int n_in,
                              void* d_out, int out_size, void* d_ws, size_t ws_size,
                              hipStream_t stream)
{
    const float* x      = (const float*)d_in[0];
    const int*   ei     = (const int*)  d_in[1];
    const float* ew     = (const float*)d_in[2];
    const float* w_root = (const float*)d_in[3];
    const float* w_rel  = (const float*)d_in[4];
    const float* b_rel  = (const float*)d_in[5];
    const float* ln_g   = (const float*)d_in[6];
    const float* ln_b   = (const float*)d_in[7];
    const float* gc1_w  = (const float*)d_in[8];
    const float* gc1_b  = (const float*)d_in[9];
    const float* bn1_g  = (const float*)d_in[10];
    const float* bn1_b  = (const float*)d_in[11];
    const float* gc2_w  = (const float*)d_in[12];
    const float* gc2_b  = (const float*)d_in[13];
    const float* bn2_g  = (const float*)d_in[14];
    const float* bn2_b  = (const float*)d_in[15];
    const float* fc_w1  = (const float*)d_in[16];
    const float* fc_b1  = (const float*)d_in[17];
    const float* fbn1_g = (const float*)d_in[18];
    const float* fbn1_b = (const float*)d_in[19];
    const float* fc_w2  = (const float*)d_in[20];
    const float* fc_b2  = (const float*)d_in[21];
    const float* fbn2_g = (const float*)d_in[22];
    const float* fbn2_b = (const float*)d_in[23];
    const float* fc1_w  = (const float*)d_in[24];
    const float* fc1_b  = (const float*)d_in[25];
    float* out = (float*)d_out;

    char* ws = (char*)d_ws;
    // layout: recs | stab | paggr (reused as o1p) | zbuf   = 181.5 MB (proven)
    const size_t off_recs  = 0;                                   // 134,217,728
    const size_t off_stab  = off_recs + (size_t)NBLK*EPB*8;       // +2,097,152
    const size_t off_paggr = off_stab + (size_t)NBLK*NBK*2;
    const size_t sz_paggr  = (size_t)RSP6*NGRP*GRP*NN*4;          // 36,175,872 (>= o1p 8,126,464)
    const size_t off_zbuf  = off_paggr + sz_paggr;
    const size_t need      = off_zbuf + (size_t)BB*KK1*4;         // 181,530,624

    if (ws_size >= need) {
        uint2*          recs  = (uint2*)(ws + off_recs);
        unsigned short* stab  = (unsigned short*)(ws + off_stab);
        float*          paggr = (float*)(ws + off_paggr);
        float*          zbuf  = (float*)(ws + off_zbuf);
        float*          o1p   = (float*)(ws + off_paggr);  // reused after k_ln_conv

        k_place4<<<NBLK, TPB, 0, stream>>>(ei, ei + EE, ew, recs, stab);
        k_replay8<<<NGRP*RSP6, 512, 0, stream>>>(recs, stab, x, paggr);
        k_ln_conv<<<BB, 512, 0, stream>>>(x, paggr,
                                         w_root, w_rel, b_rel, ln_g, ln_b,
                                         gc1_w, gc1_b, bn1_g, bn1_b,
                                         gc2_w, gc2_b, bn2_g, bn2_b, zbuf);
        k_fc1_part<<<dim3(4,4,31), 256, 0, stream>>>(zbuf, fc_w1, o1p);
        k_tail_part<<<BB, 256, 0, stream>>>(o1p, fc_b1, fbn1_g, fbn1_b,
                                       fc_w2, fc_b2, fbn2_g, fbn2_b,
                                       fc1_w, fc1_b, out);
    } else {
        // round-1 fallback (proven <= 11.6 MB ws)
        float* agg      = (float*)(ws);
        float* zbuf     = (float*)(ws + 2259968);
        float* out1_raw = (float*)(ws + 2259968 + 9039872);

        hipMemsetAsync(agg,      0, (size_t)BB*NN*sizeof(float),  stream);
        hipMemsetAsync(out1_raw, 0, (size_t)BB*HH1*sizeof(float), stream);

        k_edge<<<EE/4/256, 256, 0, stream>>>(ei, ei + EE, ew, x, agg);
        k_sample<<<BB, 256, 0, stream>>>(x, agg, w_root, w_rel, b_rel, ln_g, ln_b,
                                         gc1_w, gc1_b, bn1_g, bn1_b,
                                         gc2_w, gc2_b, bn2_g, bn2_b, zbuf);
        k_fc1<<<dim3(4,4,31), 256, 0, stream>>>(zbuf, fc_w1, out1_raw);
        k_tail<<<BB, 256, 0, stream>>>(out1_raw, fc_b1, fbn1_g, fbn1_b,
                                       fc_w2, fc_b2, fbn2_g, fbn2_b,
                                       fc1_w, fc1_b, out);
    }
}